// Round 4
// baseline (473.207 us; speedup 1.0000x reference)
//
#include <hip/hip_runtime.h>
#include <math.h>

// TGCN: bf16 feature-space GCN aggregation (fp32 accum) -> fused bf16-MFMA GRU.
// CSR-by-dst, no float atomic scatter. Weights pre-transposed to bf16 [col][k].

#define HD 128

typedef __attribute__((ext_vector_type(8))) short short8;
typedef __attribute__((ext_vector_type(4))) float f32x4;

__device__ __forceinline__ ushort f2bf(float f) {
    union { float f; unsigned u; } v; v.f = f;
    unsigned r = (v.u + 0x7FFFu + ((v.u >> 16) & 1u)) >> 16;
    return (ushort)r;
}
__device__ __forceinline__ float bf2f(ushort h) {
    union { unsigned u; float f; } v; v.u = ((unsigned)h) << 16;
    return v.f;
}
__device__ __forceinline__ float bflo(unsigned u) {
    union { unsigned u; float f; } v; v.u = u << 16; return v.f;
}
__device__ __forceinline__ float bfhi(unsigned u) {
    union { unsigned u; float f; } v; v.u = u & 0xFFFF0000u; return v.f;
}

// nf -> bf16 copy (vectorized), plus deg := 1.0 init
__global__ void prep_kernel(const float* __restrict__ nf, ushort* __restrict__ nfb,
                            float* deg, int n) {
    int idx = blockIdx.x * 256 + threadIdx.x;
    int total8 = n * (HD / 8);
    if (idx < total8) {
        const float4* p = (const float4*)(nf + (size_t)idx * 8);
        float4 x = p[0], y = p[1];
        short8 o;
        o[0] = (short)f2bf(x.x); o[1] = (short)f2bf(x.y);
        o[2] = (short)f2bf(x.z); o[3] = (short)f2bf(x.w);
        o[4] = (short)f2bf(y.x); o[5] = (short)f2bf(y.y);
        o[6] = (short)f2bf(y.z); o[7] = (short)f2bf(y.w);
        *(short8*)(nfb + (size_t)idx * 8) = o;
    }
    if (idx < n) deg[idx] = 1.0f;
}

__global__ void edge_accum_kernel(const int* __restrict__ dst,
                                  const float* __restrict__ w,
                                  float* deg, int* counts, int E) {
    int e = blockIdx.x * blockDim.x + threadIdx.x;
    if (e < E) {
        int d = dst[e];
        atomicAdd(&deg[d], w[e]);
        atomicAdd(&counts[d], 1);
    }
}

__global__ void dinv_kernel(const float* __restrict__ deg, float* dinv, int n) {
    int i = blockIdx.x * blockDim.x + threadIdx.x;
    if (i < n) {
        float d = deg[i];
        dinv[i] = (d > 0.0f) ? rsqrtf(d) : 0.0f;
    }
}

// chunk-per-thread scan: local sum -> block scan -> local prefix writeback
__global__ __launch_bounds__(1024) void scan_kernel(const int* __restrict__ counts,
                                                    int* row_ptr, int* cursor, int n) {
    __shared__ int wsum[16];
    int tid = threadIdx.x;
    int per = (n + 1023) / 1024;
    int start = tid * per;
    int end = min(start + per, n);
    int s = 0;
    for (int i = start; i < end; ++i) s += counts[i];
    int lane = tid & 63, wid = tid >> 6;
    int x = s;
    for (int off = 1; off < 64; off <<= 1) {
        int y = __shfl_up(x, off, 64);
        if (lane >= off) x += y;
    }
    if (lane == 63) wsum[wid] = x;
    __syncthreads();
    if (wid == 0) {
        int v = (lane < 16) ? wsum[lane] : 0;
        for (int off = 1; off < 16; off <<= 1) {
            int y = __shfl_up(v, off, 64);
            if (lane >= off) v += y;
        }
        if (lane < 16) wsum[lane] = v;
    }
    __syncthreads();
    int run = x - s + ((wid == 0) ? 0 : wsum[wid - 1]);  // exclusive prefix
    for (int i = start; i < end; ++i) {
        int c = counts[i];
        row_ptr[i] = run; cursor[i] = run;
        run += c;
    }
    if (tid == 1023) row_ptr[n] = run;
}

__global__ void fill_kernel(const int* __restrict__ src, const int* __restrict__ dst,
                            const float* __restrict__ w, const float* __restrict__ dinv,
                            int* cursor, int* src_s, float* norm_s, int E) {
    int e = blockIdx.x * blockDim.x + threadIdx.x;
    if (e < E) {
        int s = src[e], d = dst[e];
        int p = atomicAdd(&cursor[d], 1);
        src_s[p] = s;
        norm_s[p] = dinv[s] * w[e] * dinv[d];
    }
}

// dstT[g*J*K + j*K + k] = bf16(Wg[k*J + j])  (3 weight transposes in one launch)
__global__ void transpose3_bf16_kernel(const float* __restrict__ W0,
                                       const float* __restrict__ W1,
                                       const float* __restrict__ W2,
                                       ushort* __restrict__ dstT, int K, int J) {
    int idx = blockIdx.x * 256 + threadIdx.x;
    int per = K * J;
    if (idx < 3 * per) {
        int g = idx / per, r = idx - g * per;
        int j = r / K, k = r - j * K;
        const float* W = (g == 0) ? W0 : (g == 1) ? W1 : W2;
        dstT[idx] = f2bf(W[k * J + j]);
    }
}

// aggb[i,:] = bf16( dinv[i]^2 * nfb[i,:] + sum_e norm[e] * nfb[src[e],:] )
// 64 lanes per node (each lane owns a bf16 pair), 4 nodes per 256-thr block.
__global__ __launch_bounds__(256) void agg_feat_kernel(
        const unsigned* __restrict__ nfb32, const float* __restrict__ dinv,
        const int* __restrict__ row_ptr, const int* __restrict__ src_s,
        const float* __restrict__ norm_s, unsigned* __restrict__ aggb32, int n) {
    int t = threadIdx.x & 63;            // column pair
    int grp = threadIdx.x >> 6;
    int i = blockIdx.x * 4 + grp;
    if (i >= n) return;
    float di = dinv[i];
    unsigned uself = nfb32[(size_t)i * 64 + t];
    float a0 = di * di * bflo(uself);
    float a1 = di * di * bfhi(uself);
    int e0 = row_ptr[i], e1 = row_ptr[i + 1];
    for (int e = e0; e < e1; e += 8) {
        unsigned v[8]; float w[8];
#pragma unroll
        for (int u = 0; u < 8; ++u) {
            int ee = e + u;
            bool ok = ee < e1;
            int s = ok ? src_s[ee] : src_s[e0];
            w[u] = ok ? norm_s[ee] : 0.0f;
            v[u] = nfb32[(size_t)s * 64 + t];
        }
#pragma unroll
        for (int u = 0; u < 8; ++u) {
            a0 += w[u] * bflo(v[u]);
            a1 += w[u] * bfhi(v[u]);
        }
    }
    aggb32[(size_t)i * 64 + t] = (unsigned)f2bf(a0) | ((unsigned)f2bf(a1) << 16);
}

// Fused GRU via bf16 MFMA. 32-node tile, 6 waves:
//   waves 0,1 -> z cols 0..127 ; waves 2,3 -> r ; waves 4,5 -> h
__global__ __launch_bounds__(384) void gru_mfma_kernel(
        const ushort* __restrict__ aggb, const float* __restrict__ h0,
        const ushort* __restrict__ WcatT,
        const ushort* __restrict__ lzT, const ushort* __restrict__ lrT,
        const ushort* __restrict__ lhT,
        const float* __restrict__ bz, const float* __restrict__ br,
        const float* __restrict__ bh,
        const float* __restrict__ lzb, const float* __restrict__ lrb,
        const float* __restrict__ lhb,
        float* __restrict__ hout, int n) {
    __shared__ ushort Aag[32][136];   // agg tile bf16 (pad 8 -> stride 272B)
    __shared__ ushort Ah0[32][136];   // h0 tile bf16
    __shared__ ushort C1s[32][392];   // C1 = agg@Wcat + b  (384 cols, pad 8)
    __shared__ ushort hqs[32][136];   // h0*r
    __shared__ ushort zsb[32][128];   // z gate
    int t = threadIdx.x;
    int i0 = blockIdx.x * 32;

    // stage agg + h0 tiles (rows >= n zero-filled)
    for (int idx = t; idx < 512; idx += 384) {
        int row = idx >> 4, c8 = idx & 15;
        int node = i0 + row;
        if (node < n) {
            *(short8*)&Aag[row][c8 * 8] =
                *(const short8*)(aggb + (size_t)node * HD + c8 * 8);
            const float* hp = h0 + (size_t)node * HD + c8 * 8;
            float4 ha = *(const float4*)hp;
            float4 hb = *(const float4*)(hp + 4);
            short8 hv;
            hv[0] = (short)f2bf(ha.x); hv[1] = (short)f2bf(ha.y);
            hv[2] = (short)f2bf(ha.z); hv[3] = (short)f2bf(ha.w);
            hv[4] = (short)f2bf(hb.x); hv[5] = (short)f2bf(hb.y);
            hv[6] = (short)f2bf(hb.z); hv[7] = (short)f2bf(hb.w);
            *(short8*)&Ah0[row][c8 * 8] = hv;
        } else {
            short8 zz = {0, 0, 0, 0, 0, 0, 0, 0};
            *(short8*)&Aag[row][c8 * 8] = zz;
            *(short8*)&Ah0[row][c8 * 8] = zz;
        }
    }
    __syncthreads();

    int wave = t >> 6, lane = t & 63;
    int g = wave >> 1;                 // gate: 0=z 1=r 2=h
    int colbase = wave * 64;           // global col in [0,384)
    int lc0 = (wave & 1) * 64;         // col within gate
    int rlo = lane & 15;
    int koff = (lane >> 4) * 8;
    int rbase = (lane >> 4) * 4;       // C/D row group

    f32x4 acc[2][4];
    const f32x4 zero4 = {0.f, 0.f, 0.f, 0.f};
#pragma unroll
    for (int rf = 0; rf < 2; ++rf)
#pragma unroll
        for (int cf = 0; cf < 4; ++cf) acc[rf][cf] = zero4;

    // ---- Phase 1: C1 = agg @ Wcat  (K=128) ----
#pragma unroll
    for (int ks = 0; ks < 4; ++ks) {
        short8 af0 = *(const short8*)&Aag[rlo][ks * 32 + koff];
        short8 af1 = *(const short8*)&Aag[16 + rlo][ks * 32 + koff];
        short8 bf[4];
#pragma unroll
        for (int cf = 0; cf < 4; ++cf) {
            int col = colbase + cf * 16 + rlo;
            bf[cf] = *(const short8*)(WcatT + (size_t)col * 128 + ks * 32 + koff);
        }
#pragma unroll
        for (int cf = 0; cf < 4; ++cf) {
            acc[0][cf] = __builtin_amdgcn_mfma_f32_16x16x32_bf16(af0, bf[cf], acc[0][cf], 0, 0, 0);
            acc[1][cf] = __builtin_amdgcn_mfma_f32_16x16x32_bf16(af1, bf[cf], acc[1][cf], 0, 0, 0);
        }
    }
    {
        const float* gb = (g == 0) ? bz : (g == 1) ? br : bh;
#pragma unroll
        for (int cf = 0; cf < 4; ++cf) {
            int bcol = lc0 + cf * 16 + rlo;
            int col = colbase + cf * 16 + rlo;
            float bv = gb[bcol];
#pragma unroll
            for (int rf = 0; rf < 2; ++rf)
#pragma unroll
                for (int i = 0; i < 4; ++i) {
                    int row = rf * 16 + rbase + i;
                    C1s[row][col] = f2bf(acc[rf][cf][i] + bv);
                }
        }
    }
    __syncthreads();

    // ---- Phase 2: gates ----
#pragma unroll
    for (int rf = 0; rf < 2; ++rf)
#pragma unroll
        for (int cf = 0; cf < 4; ++cf) acc[rf][cf] = zero4;

    const ushort* lT = (g == 0) ? lzT : (g == 1) ? lrT : lhT;
    if (g < 2) {
        // [C1g | h0] @ lT   (K=256)
#pragma unroll
        for (int ks = 0; ks < 4; ++ks) {
            short8 af0 = *(const short8*)&C1s[rlo][g * 128 + ks * 32 + koff];
            short8 af1 = *(const short8*)&C1s[16 + rlo][g * 128 + ks * 32 + koff];
            short8 bf[4];
#pragma unroll
            for (int cf = 0; cf < 4; ++cf) {
                int jc = lc0 + cf * 16 + rlo;
                bf[cf] = *(const short8*)(lT + (size_t)jc * 256 + ks * 32 + koff);
            }
#pragma unroll
            for (int cf = 0; cf < 4; ++cf) {
                acc[0][cf] = __builtin_amdgcn_mfma_f32_16x16x32_bf16(af0, bf[cf], acc[0][cf], 0, 0, 0);
                acc[1][cf] = __builtin_amdgcn_mfma_f32_16x16x32_bf16(af1, bf[cf], acc[1][cf], 0, 0, 0);
            }
        }
#pragma unroll
        for (int ks = 0; ks < 4; ++ks) {
            short8 af0 = *(const short8*)&Ah0[rlo][ks * 32 + koff];
            short8 af1 = *(const short8*)&Ah0[16 + rlo][ks * 32 + koff];
            short8 bf[4];
#pragma unroll
            for (int cf = 0; cf < 4; ++cf) {
                int jc = lc0 + cf * 16 + rlo;
                bf[cf] = *(const short8*)(lT + (size_t)jc * 256 + 128 + ks * 32 + koff);
            }
#pragma unroll
            for (int cf = 0; cf < 4; ++cf) {
                acc[0][cf] = __builtin_amdgcn_mfma_f32_16x16x32_bf16(af0, bf[cf], acc[0][cf], 0, 0, 0);
                acc[1][cf] = __builtin_amdgcn_mfma_f32_16x16x32_bf16(af1, bf[cf], acc[1][cf], 0, 0, 0);
            }
        }
        const float* lb = (g == 0) ? lzb : lrb;
#pragma unroll
        for (int cf = 0; cf < 4; ++cf) {
            int bcol = lc0 + cf * 16 + rlo;
            float bv = lb[bcol];
#pragma unroll
            for (int rf = 0; rf < 2; ++rf)
#pragma unroll
                for (int i = 0; i < 4; ++i) {
                    int row = rf * 16 + rbase + i;
                    float s = 1.0f / (1.0f + expf(-(acc[rf][cf][i] + bv)));
                    if (g == 0) {
                        zsb[row][bcol] = f2bf(s);
                    } else {
                        float hv = bf2f(Ah0[row][bcol]);
                        hqs[row][bcol] = f2bf(s * hv);
                    }
                }
        }
    } else {
        // hp = C1h @ lhT_top   (K=128), keep in regs
#pragma unroll
        for (int ks = 0; ks < 4; ++ks) {
            short8 af0 = *(const short8*)&C1s[rlo][256 + ks * 32 + koff];
            short8 af1 = *(const short8*)&C1s[16 + rlo][256 + ks * 32 + koff];
            short8 bf[4];
#pragma unroll
            for (int cf = 0; cf < 4; ++cf) {
                int jc = lc0 + cf * 16 + rlo;
                bf[cf] = *(const short8*)(lT + (size_t)jc * 256 + ks * 32 + koff);
            }
#pragma unroll
            for (int cf = 0; cf < 4; ++cf) {
                acc[0][cf] = __builtin_amdgcn_mfma_f32_16x16x32_bf16(af0, bf[cf], acc[0][cf], 0, 0, 0);
                acc[1][cf] = __builtin_amdgcn_mfma_f32_16x16x32_bf16(af1, bf[cf], acc[1][cf], 0, 0, 0);
            }
        }
    }
    __syncthreads();

    // ---- Phase 3 (h waves): hp += (h0*r) @ lhT_bot; combine; write ----
    if (g == 2) {
#pragma unroll
        for (int ks = 0; ks < 4; ++ks) {
            short8 af0 = *(const short8*)&hqs[rlo][ks * 32 + koff];
            short8 af1 = *(const short8*)&hqs[16 + rlo][ks * 32 + koff];
            short8 bf[4];
#pragma unroll
            for (int cf = 0; cf < 4; ++cf) {
                int jc = lc0 + cf * 16 + rlo;
                bf[cf] = *(const short8*)(lhT + (size_t)jc * 256 + 128 + ks * 32 + koff);
            }
#pragma unroll
            for (int cf = 0; cf < 4; ++cf) {
                acc[0][cf] = __builtin_amdgcn_mfma_f32_16x16x32_bf16(af0, bf[cf], acc[0][cf], 0, 0, 0);
                acc[1][cf] = __builtin_amdgcn_mfma_f32_16x16x32_bf16(af1, bf[cf], acc[1][cf], 0, 0, 0);
            }
        }
#pragma unroll
        for (int cf = 0; cf < 4; ++cf) {
            int bcol = lc0 + cf * 16 + rlo;
            float bv = lhb[bcol];
#pragma unroll
            for (int rf = 0; rf < 2; ++rf)
#pragma unroll
                for (int i = 0; i < 4; ++i) {
                    int row = rf * 16 + rbase + i;
                    int node = i0 + row;
                    if (node < n) {
                        float ht = tanhf(acc[rf][cf][i] + bv);
                        float z = bf2f(zsb[row][bcol]);
                        float h0v = bf2f(Ah0[row][bcol]);
                        hout[(size_t)node * HD + bcol] = z * h0v + (1.0f - z) * ht;
                    }
                }
        }
    }
}

__global__ __launch_bounds__(128) void pool_kernel(
        const float* __restrict__ hout, const int* __restrict__ nids,
        float* pooled, int U) {
    int t = threadIdx.x;
    float pa = 0.0f;
    for (int u = blockIdx.x; u < U; u += gridDim.x) {
        int nid = nids[u];
        pa += fmaxf(hout[(size_t)nid * HD + t], 0.0f);
    }
    atomicAdd(&pooled[t], pa);
}

__global__ __launch_bounds__(128) void decoder_kernel(
        const float* __restrict__ pooled, float invU,
        const float* __restrict__ linW, const float* __restrict__ linb,
        const float* __restrict__ dnW, const float* __restrict__ dnb,
        const float* __restrict__ outW, const float* __restrict__ outb,
        float* pred, int C) {
    __shared__ float sh[HD];
    int t = threadIdx.x;
    sh[t] = pooled[t] * invU;
    __syncthreads();
    float v = linb[t];
    for (int k = 0; k < HD; ++k) v += sh[k] * linW[k * HD + t];
    __syncthreads();
    sh[t] = v;
    __syncthreads();
    float d = dnb[t];
    for (int k = 0; k < HD; ++k) d += sh[k] * dnW[k * HD + t];
    d = fmaxf(d, 0.0f);
    __syncthreads();
    sh[t] = d;
    __syncthreads();
    if (t < C) {
        float p = outb[t];
        for (int k = 0; k < HD; ++k) p += sh[k] * outW[k * C + t];
        pred[t] = 1.0f / (1.0f + expf(-p));
    }
}

extern "C" void kernel_launch(void* const* d_in, const int* in_sizes, int n_in,
                              void* d_out, int out_size, void* d_ws, size_t ws_size,
                              hipStream_t stream) {
    const float* node_feat = (const float*)d_in[0];
    const float* edge_w    = (const float*)d_in[1];
    const float* h0        = (const float*)d_in[2];
    const float* Wz  = (const float*)d_in[3];  const float* bz  = (const float*)d_in[4];
    const float* Wr  = (const float*)d_in[5];  const float* br  = (const float*)d_in[6];
    const float* Wh  = (const float*)d_in[7];  const float* bh  = (const float*)d_in[8];
    const float* lzW = (const float*)d_in[9];  const float* lzb = (const float*)d_in[10];
    const float* lrW = (const float*)d_in[11]; const float* lrb = (const float*)d_in[12];
    const float* lhW = (const float*)d_in[13]; const float* lhb = (const float*)d_in[14];
    const float* linW= (const float*)d_in[15]; const float* linb= (const float*)d_in[16];
    const float* dnW = (const float*)d_in[17]; const float* dnb = (const float*)d_in[18];
    const float* outW= (const float*)d_in[19]; const float* outb= (const float*)d_in[20];
    const int* src  = (const int*)d_in[21];
    const int* dst  = (const int*)d_in[22];
    const int* nids = (const int*)d_in[23];

    const int N = in_sizes[2] / HD;
    const int E = in_sizes[1];
    const int U = in_sizes[23];
    const int C = in_sizes[20];

    float* out  = (float*)d_out;
    float* pred = out;          // [C]
    float* hout = out + C;      // [N,H]

    // workspace layout (16B-aligned chunks)
    char* p = (char*)d_ws;
    auto alloc = [&](size_t bytes) { char* r = p; p += (bytes + 15) & ~(size_t)15; return r; };
    float* deg    = (float*)alloc((size_t)N * 4);
    float* dinv   = (float*)alloc((size_t)N * 4);
    float* norm_s = (float*)alloc((size_t)E * 4);
    float* pooled = (float*)alloc(HD * 4);
    int*   counts = (int*)alloc((size_t)N * 4);
    int*   row_ptr= (int*)alloc((size_t)(N + 1) * 4);
    int*   cursor = (int*)alloc((size_t)N * 4);
    int*   src_s  = (int*)alloc((size_t)E * 4);
    ushort* nfb   = (ushort*)alloc((size_t)N * HD * 2);
    ushort* aggb  = (ushort*)alloc((size_t)N * HD * 2);
    ushort* WcatT = (ushort*)alloc((size_t)384 * 128 * 2);
    ushort* lT3   = (ushort*)alloc((size_t)3 * 128 * 256 * 2);
    ushort* lzT = lT3;
    ushort* lrT = lT3 + 128 * 256;
    ushort* lhT = lT3 + 2 * 128 * 256;

    hipMemsetAsync(counts, 0, (size_t)N * sizeof(int), stream);
    hipMemsetAsync(pooled, 0, HD * sizeof(float), stream);

    int prep_items = N * (HD / 8);  // covers N too
    prep_kernel<<<(prep_items + 255) / 256, 256, 0, stream>>>(node_feat, nfb, deg, N);
    edge_accum_kernel<<<(E + 255) / 256, 256, 0, stream>>>(dst, edge_w, deg, counts, E);
    dinv_kernel<<<(N + 255) / 256, 256, 0, stream>>>(deg, dinv, N);
    scan_kernel<<<1, 1024, 0, stream>>>(counts, row_ptr, cursor, N);
    fill_kernel<<<(E + 255) / 256, 256, 0, stream>>>(src, dst, edge_w, dinv, cursor,
                                                     src_s, norm_s, E);
    transpose3_bf16_kernel<<<(3 * 128 * 128 + 255) / 256, 256, 0, stream>>>(
        Wz, Wr, Wh, WcatT, 128, 128);
    transpose3_bf16_kernel<<<(3 * 256 * 128 + 255) / 256, 256, 0, stream>>>(
        lzW, lrW, lhW, lT3, 256, 128);

    agg_feat_kernel<<<(N + 3) / 4, 256, 0, stream>>>(
        (const unsigned*)nfb, dinv, row_ptr, src_s, norm_s, (unsigned*)aggb, N);
    gru_mfma_kernel<<<(N + 31) / 32, 384, 0, stream>>>(
        aggb, h0, WcatT, lzT, lrT, lhT, bz, br, bh, lzb, lrb, lhb, hout, N);
    pool_kernel<<<512, 128, 0, stream>>>(hout, nids, pooled, U);
    decoder_kernel<<<1, 128, 0, stream>>>(pooled, 1.0f / (float)U,
                                          linW, linb, dnW, dnb, outW, outb, pred, C);
}